// Round 5
// baseline (239.272 us; speedup 1.0000x reference)
//
#include <hip/hip_runtime.h>

typedef _Float16 f16;
typedef _Float16 f16x8 __attribute__((ext_vector_type(8)));
typedef _Float16 f16x4 __attribute__((ext_vector_type(4)));
typedef float    f32x4 __attribute__((ext_vector_type(4)));

// Problem: B=2, S=2048, E=2048, H=16, HKV=4, D=128, WINDOW=256
// Reference quirk: q is ALSO indexed by idx=repeat(arange(4),4) -> only q heads
// 0..3 (Wq rows 0..511) are used; output head i = attn_g (g=i//4), so Wo is
// pre-folded: Wr[e,g*128+d] = sum_j Wo[e,(4g+j)*128+d].
// I/O: inputs f32, output f32. Internals: fp16 storage + fp16 MFMA, f32 accum
// (bf16 was 1.5x over the abs threshold; fp16's 2^-11 eps gives ~8x margin).

// ---------------------------------------------------------------------------
// Wo fold (f32 in, f16 out)
// ---------------------------------------------------------------------------
__global__ __launch_bounds__(256)
void wo_reduce(const float* __restrict__ Wo, f16* __restrict__ Wr)
{
    size_t t = (size_t)blockIdx.x * 256 + threadIdx.x;  // 262144 threads
    size_t o = t * 4;
    int e = (int)(o >> 9);
    int c = (int)(o & 511);
    int g = c >> 7, d0 = c & 127;
    const float* src = Wo + (size_t)e * 2048 + g * 512 + d0;
    float4 a0 = *(const float4*)(src);
    float4 a1 = *(const float4*)(src + 128);
    float4 a2 = *(const float4*)(src + 256);
    float4 a3 = *(const float4*)(src + 384);
    f16x4 ob;
    ob[0] = (f16)(a0.x + a1.x + a2.x + a3.x);
    ob[1] = (f16)(a0.y + a1.y + a2.y + a3.y);
    ob[2] = (f16)(a0.z + a1.z + a2.z + a3.z);
    ob[3] = (f16)(a0.w + a1.w + a2.w + a3.w);
    *(f16x4*)(Wr + o) = ob;
}

// ---------------------------------------------------------------------------
// Fused QKV projection GEMM, f32 inputs converted to f16 during LDS staging.
// C[m,n] = sum_k X[m,k]*W[n,k]; M=4096, N=512, K=2048.
// z selects (Wq rows 0..511 | Wk | Wv). z<2: write (B,4,S,D); z==2: (B,4,D,S).
// ---------------------------------------------------------------------------
__global__ __launch_bounds__(256)
void qkv_gemm(const float* __restrict__ X, const float* __restrict__ Wq,
              const float* __restrict__ Wk, const float* __restrict__ Wv,
              f16* __restrict__ Qo, f16* __restrict__ Ko, f16* __restrict__ Vo)
{
    const int z = blockIdx.z;
    const float* Bw = (z == 0) ? Wq : (z == 1) ? Wk : Wv;
    f16* C = (z == 0) ? Qo : (z == 1) ? Ko : Vo;
    const int K = 2048;

    __shared__ __align__(16) f16 As[128 * 32];
    __shared__ __align__(16) f16 Bs[128 * 32];

    const int tid = threadIdx.x;
    const int wave = tid >> 6, lane = tid & 63;
    const int lrow = lane & 15, lquad = lane >> 4;
    const int wr = wave >> 1, wc = wave & 1;
    const int m0 = blockIdx.y * 128, n0 = blockIdx.x * 128;

    f32x4 acc[4][4];
    const f32x4 z4 = {0.f, 0.f, 0.f, 0.f};
    for (int i = 0; i < 4; i++) for (int j = 0; j < 4; j++) acc[i][j] = z4;

    for (int k0 = 0; k0 < K; k0 += 32) {
        float4 ax[2][2], bx[2][2];
        for (int i = 0; i < 2; i++) {
            int slot = i * 256 + tid;               // [0,512)
            int row = slot >> 2, kc = slot & 3;     // row<128, kc*8 in [0,32)
            const float* pa = X  + (size_t)(m0 + row) * K + k0 + kc * 8;
            const float* pb = Bw + (size_t)(n0 + row) * K + k0 + kc * 8;
            ax[i][0] = *(const float4*)pa; ax[i][1] = *(const float4*)(pa + 4);
            bx[i][0] = *(const float4*)pb; bx[i][1] = *(const float4*)(pb + 4);
        }
        __syncthreads();
        for (int i = 0; i < 2; i++) {
            int slot = i * 256 + tid;
            f16x8 av, bv;
            av[0] = (f16)ax[i][0].x; av[1] = (f16)ax[i][0].y;
            av[2] = (f16)ax[i][0].z; av[3] = (f16)ax[i][0].w;
            av[4] = (f16)ax[i][1].x; av[5] = (f16)ax[i][1].y;
            av[6] = (f16)ax[i][1].z; av[7] = (f16)ax[i][1].w;
            bv[0] = (f16)bx[i][0].x; bv[1] = (f16)bx[i][0].y;
            bv[2] = (f16)bx[i][0].z; bv[3] = (f16)bx[i][0].w;
            bv[4] = (f16)bx[i][1].x; bv[5] = (f16)bx[i][1].y;
            bv[6] = (f16)bx[i][1].z; bv[7] = (f16)bx[i][1].w;
            *(f16x8*)(As + slot * 8) = av;
            *(f16x8*)(Bs + slot * 8) = bv;
        }
        __syncthreads();
        f16x8 af[4], bfr[4];
        for (int mt = 0; mt < 4; mt++)
            af[mt]  = *(const f16x8*)(As + (wr * 64 + mt * 16 + lrow) * 32 + lquad * 8);
        for (int nt = 0; nt < 4; nt++)
            bfr[nt] = *(const f16x8*)(Bs + (wc * 64 + nt * 16 + lrow) * 32 + lquad * 8);
        for (int mt = 0; mt < 4; mt++)
            for (int nt = 0; nt < 4; nt++)
                acc[mt][nt] = __builtin_amdgcn_mfma_f32_16x16x32_f16(af[mt], bfr[nt], acc[mt][nt], 0, 0, 0);
    }

    if (z < 2) {
        for (int mt = 0; mt < 4; mt++) {
            int mbase = m0 + wr * 64 + mt * 16 + lquad * 4;
            for (int r = 0; r < 4; r++) {
                int m = mbase + r;
                int b = m >> 11, s = m & 2047;
                for (int nt = 0; nt < 4; nt++) {
                    int n = n0 + wc * 64 + nt * 16 + lrow;
                    int h = n >> 7, d = n & 127;
                    C[(size_t)(((b * 4 + h) << 11) + s) * 128 + d] = (f16)acc[mt][nt][r];
                }
            }
        }
    } else {
        for (int mt = 0; mt < 4; mt++) {
            int mbase = m0 + wr * 64 + mt * 16 + lquad * 4;
            int b = mbase >> 11, s = mbase & 2047;
            for (int nt = 0; nt < 4; nt++) {
                int n = n0 + wc * 64 + nt * 16 + lrow;
                int h = n >> 7, d = n & 127;
                f16x4 pk;
                for (int r = 0; r < 4; r++) pk[r] = (f16)acc[mt][nt][r];
                *(f16x4*)(C + ((size_t)((b * 4 + h) * 128 + d) << 11) + s) = pk;
            }
        }
    }
}

// ---------------------------------------------------------------------------
// Sliding-window attention, one wave per 16 query rows.
// Q,K: (B,4,S,D); V: (B,4,D,S) transposed; AO: (B,S,512)
// ---------------------------------------------------------------------------
__global__ __launch_bounds__(64)
void attn_win(const f16* __restrict__ Q, const f16* __restrict__ Kc,
              const f16* __restrict__ Vt, f16* __restrict__ AO)
{
    const int bg = blockIdx.y;
    const int b = bg >> 2, g = bg & 3;
    const int qbase = blockIdx.x * 16;
    const int lane = threadIdx.x;
    const int lrow = lane & 15, lquad = lane >> 4;

    const f16* Qb = Q  + (size_t)(b * 4 + g) * (2048 * 128);
    const f16* Kb = Kc + (size_t)(b * 4 + g) * (2048 * 128);
    const f16* Vb = Vt + (size_t)(b * 4 + g) * (128 * 2048);

    __shared__ __align__(16) f16 Pl[16 * 128];

    f16x8 qf[4];
    for (int ks = 0; ks < 4; ks++)
        qf[ks] = *(const f16x8*)(Qb + (size_t)(qbase + lrow) * 128 + ks * 32 + lquad * 8);

    float m_i[4], l_i[4];
    f32x4 oa[8];
    const f32x4 z4 = {0.f, 0.f, 0.f, 0.f};
    for (int r = 0; r < 4; r++) { m_i[r] = -30000.f; l_i[r] = 0.f; }
    for (int nt = 0; nt < 8; nt++) oa[nt] = z4;

    const int t0 = (qbase >= 256) ? (((qbase - 255) >> 7) << 7) : 0;
    for (int kt = t0; kt <= qbase + 15; kt += 128) {
        f32x4 sc[8];
        for (int nt = 0; nt < 8; nt++) sc[nt] = z4;
        for (int nt = 0; nt < 8; nt++) {
            for (int ks = 0; ks < 4; ks++) {
                f16x8 kf = *(const f16x8*)(Kb + (size_t)(kt + nt * 16 + lrow) * 128 + ks * 32 + lquad * 8);
                sc[nt] = __builtin_amdgcn_mfma_f32_16x16x32_f16(qf[ks], kf, sc[nt], 0, 0, 0);
            }
        }
        for (int r = 0; r < 4; r++) {
            const int qi = qbase + lquad * 4 + r;
            float rmax = -60000.f;
            for (int nt = 0; nt < 8; nt++) {
                int kj = kt + nt * 16 + lrow;
                float sval = sc[nt][r];
                bool ok = (kj <= qi) && (kj + 256 > qi);
                sval = ok ? sval : -60000.f;
                sc[nt][r] = sval;
                rmax = fmaxf(rmax, sval);
            }
            rmax = fmaxf(rmax, __shfl_xor(rmax, 1));
            rmax = fmaxf(rmax, __shfl_xor(rmax, 2));
            rmax = fmaxf(rmax, __shfl_xor(rmax, 4));
            rmax = fmaxf(rmax, __shfl_xor(rmax, 8));
            float mold = m_i[r];
            float mnew = fmaxf(mold, rmax);
            float alpha = __expf(mold - mnew);
            m_i[r] = mnew;
            float rsum = 0.f;
            for (int nt = 0; nt < 8; nt++) {
                float p = __expf(sc[nt][r] - mnew);
                sc[nt][r] = p;
                rsum += p;
            }
            rsum += __shfl_xor(rsum, 1);
            rsum += __shfl_xor(rsum, 2);
            rsum += __shfl_xor(rsum, 4);
            rsum += __shfl_xor(rsum, 8);
            l_i[r] = l_i[r] * alpha + rsum;
            for (int nt = 0; nt < 8; nt++) oa[nt][r] *= alpha;
        }
        for (int nt = 0; nt < 8; nt++)
            for (int r = 0; r < 4; r++)
                Pl[(lquad * 4 + r) * 128 + nt * 16 + lrow] = (f16)sc[nt][r];
        __syncthreads();
        f16x8 pf[4];
        for (int ks = 0; ks < 4; ks++)
            pf[ks] = *(const f16x8*)(Pl + lrow * 128 + ks * 32 + lquad * 8);
        for (int nt = 0; nt < 8; nt++) {
            for (int ks = 0; ks < 4; ks++) {
                f16x8 vf = *(const f16x8*)(Vb + (size_t)(nt * 16 + lrow) * 2048 + kt + ks * 32 + lquad * 8);
                oa[nt] = __builtin_amdgcn_mfma_f32_16x16x32_f16(pf[ks], vf, oa[nt], 0, 0, 0);
            }
        }
        __syncthreads();
    }
    float inv[4];
    for (int r = 0; r < 4; r++) inv[r] = (l_i[r] > 0.f) ? 1.f / l_i[r] : 0.f;
    for (int nt = 0; nt < 8; nt++) {
        for (int r = 0; r < 4; r++) {
            int q = qbase + lquad * 4 + r;
            int d = nt * 16 + lrow;
            AO[(size_t)(b * 2048 + q) * 512 + g * 128 + d] = (f16)(oa[nt][r] * inv[r]);
        }
    }
}

// ---------------------------------------------------------------------------
// Output GEMM: out[m,n] = sum_k AO[m,k]*Wr[n,k] + bo[n]; M=4096, N=2048, K=512
// OUTPUT IS FLOAT32.
// ---------------------------------------------------------------------------
__global__ __launch_bounds__(256)
void out_gemm(const f16* __restrict__ A, const f16* __restrict__ Bw,
              const float* __restrict__ bias, float* __restrict__ C)
{
    const int K = 512, N = 2048;
    __shared__ __align__(16) f16 As[128 * 32];
    __shared__ __align__(16) f16 Bs[128 * 32];

    const int tid = threadIdx.x;
    const int wave = tid >> 6, lane = tid & 63;
    const int lrow = lane & 15, lquad = lane >> 4;
    const int wr = wave >> 1, wc = wave & 1;
    const int m0 = blockIdx.y * 128, n0 = blockIdx.x * 128;

    f32x4 acc[4][4];
    const f32x4 z4 = {0.f, 0.f, 0.f, 0.f};
    for (int i = 0; i < 4; i++) for (int j = 0; j < 4; j++) acc[i][j] = z4;

    for (int k0 = 0; k0 < K; k0 += 32) {
        f16x8 av[2], bv[2];
        for (int i = 0; i < 2; i++) {
            int slot = i * 256 + tid;
            int row = slot >> 2, kc = slot & 3;
            av[i] = *(const f16x8*)(A  + (size_t)(m0 + row) * K + k0 + kc * 8);
            bv[i] = *(const f16x8*)(Bw + (size_t)(n0 + row) * K + k0 + kc * 8);
        }
        __syncthreads();
        for (int i = 0; i < 2; i++) {
            int slot = i * 256 + tid;
            *(f16x8*)(As + slot * 8) = av[i];
            *(f16x8*)(Bs + slot * 8) = bv[i];
        }
        __syncthreads();
        f16x8 af[4], bfr[4];
        for (int mt = 0; mt < 4; mt++)
            af[mt]  = *(const f16x8*)(As + (wr * 64 + mt * 16 + lrow) * 32 + lquad * 8);
        for (int nt = 0; nt < 4; nt++)
            bfr[nt] = *(const f16x8*)(Bs + (wc * 64 + nt * 16 + lrow) * 32 + lquad * 8);
        for (int mt = 0; mt < 4; mt++)
            for (int nt = 0; nt < 4; nt++)
                acc[mt][nt] = __builtin_amdgcn_mfma_f32_16x16x32_f16(af[mt], bfr[nt], acc[mt][nt], 0, 0, 0);
    }

    for (int nt = 0; nt < 4; nt++) {
        int n = n0 + wc * 64 + nt * 16 + lrow;
        float bv2 = bias[n];
        for (int mt = 0; mt < 4; mt++) {
            int mbase = m0 + wr * 64 + mt * 16 + lquad * 4;
            for (int r = 0; r < 4; r++)
                C[(size_t)(mbase + r) * N + n] = acc[mt][nt][r] + bv2;
        }
    }
}

// ---------------------------------------------------------------------------
extern "C" void kernel_launch(void* const* d_in, const int* in_sizes, int n_in,
                              void* d_out, int out_size, void* d_ws, size_t ws_size,
                              hipStream_t stream)
{
    const float* x  = (const float*)d_in[0];
    const float* Wq = (const float*)d_in[1];
    const float* Wk = (const float*)d_in[2];
    const float* Wv = (const float*)d_in[3];
    const float* Wo = (const float*)d_in[4];
    const float* bo = (const float*)d_in[5];
    float* out = (float*)d_out;

    f16* Wr  = (f16*)d_ws;             // 1048576 elems (folded Wo: 2048x512)
    f16* Qws = Wr  + 1048576;          // 2097152 (B,4,S,D)
    f16* Kws = Qws + 2097152;          // 2097152
    f16* Vws = Kws + 2097152;          // 2097152 (B,4,D,S transposed)
    f16* AO  = Vws + 2097152;          // 2097152 (B,S,512)
    // total 9,437,184 f16 elems = 18 MiB

    wo_reduce<<<dim3(1024), 256, 0, stream>>>(Wo, Wr);
    qkv_gemm<<<dim3(4, 32, 3), 256, 0, stream>>>(x, Wq, Wk, Wv, Qws, Kws, Vws);
    attn_win<<<dim3(128, 8), 64, 0, stream>>>(Qws, Kws, Vws, AO);
    out_gemm<<<dim3(16, 32), 256, 0, stream>>>(AO, Wr, bo, out);
}

// Round 6
// 215.584 us; speedup vs baseline: 1.1099x; 1.1099x over previous
//
#include <hip/hip_runtime.h>

typedef _Float16 f16;
typedef _Float16 f16x8 __attribute__((ext_vector_type(8)));
typedef _Float16 f16x4 __attribute__((ext_vector_type(4)));
typedef float    f32x4 __attribute__((ext_vector_type(4)));

// Problem: B=2, S=2048, E=2048, H=16, HKV=4, D=128, WINDOW=256
// Reference quirk: q is ALSO indexed by idx=repeat(arange(4),4) -> only q heads
// 0..3 (Wq rows 0..511) used; output head i = attn_{i//4}, so Wo pre-folds:
// Wr[e,g*128+d] = sum_j Wo[e,(4g+j)*128+d].
// I/O: inputs f32, output f32. Internals: f16 storage + f16 MFMA, f32 accum.

__device__ __forceinline__ void load_lds16(const void* g, void* l) {
    __builtin_amdgcn_global_load_lds(
        (__attribute__((address_space(1))) void*)(g),
        (__attribute__((address_space(3))) void*)(l), 16, 0, 0);
}

// ---------------------------------------------------------------------------
// Pre-pass: f32->f16 convert (X, Wq rows 0..511, Wk, Wv) + Wo GQA fold.
// blocks [0,11264): cvt 11534336 elems; blocks [11264,12288): fold.
// ---------------------------------------------------------------------------
__global__ __launch_bounds__(256)
void cvt_fold(const float* __restrict__ X, const float* __restrict__ Wq,
              const float* __restrict__ Wk, const float* __restrict__ Wv,
              const float* __restrict__ Wo,
              f16* __restrict__ Xh, f16* __restrict__ Wqh,
              f16* __restrict__ Wkh, f16* __restrict__ Wvh, f16* __restrict__ Wr)
{
    int blk = blockIdx.x;
    if (blk < 11264) {
        size_t o = ((size_t)blk * 256 + threadIdx.x) * 4;
        const float* src; f16* dst; size_t off;
        if (o < 8388608)       { src = X;  dst = Xh;  off = o; }
        else if (o < 9437184)  { src = Wq; dst = Wqh; off = o - 8388608; }
        else if (o < 10485760) { src = Wk; dst = Wkh; off = o - 9437184; }
        else                   { src = Wv; dst = Wvh; off = o - 10485760; }
        float4 v = *(const float4*)(src + off);
        f16x4 b;
        b[0] = (f16)v.x; b[1] = (f16)v.y; b[2] = (f16)v.z; b[3] = (f16)v.w;
        *(f16x4*)(dst + off) = b;
    } else {
        size_t t = (size_t)(blk - 11264) * 256 + threadIdx.x;  // < 262144
        size_t o = t * 4;
        int e = (int)(o >> 9);
        int c = (int)(o & 511);
        int g = c >> 7, d0 = c & 127;
        const float* src = Wo + (size_t)e * 2048 + g * 512 + d0;
        float4 a0 = *(const float4*)(src);
        float4 a1 = *(const float4*)(src + 128);
        float4 a2 = *(const float4*)(src + 256);
        float4 a3 = *(const float4*)(src + 384);
        f16x4 ob;
        ob[0] = (f16)(a0.x + a1.x + a2.x + a3.x);
        ob[1] = (f16)(a0.y + a1.y + a2.y + a3.y);
        ob[2] = (f16)(a0.z + a1.z + a2.z + a3.z);
        ob[3] = (f16)(a0.w + a1.w + a2.w + a3.w);
        *(f16x4*)(Wr + o) = ob;
    }
}

// ---------------------------------------------------------------------------
// Fused QKV projection GEMM (f16 in via global_load_lds width-16).
// C[m,n] = sum_k X[m,k]*W[n,k]; M=4096, N=512, K=2048.
// z selects (Wq' | Wk | Wv). z<2: write (B,4,S,D); z==2: (B,4,D,S) transposed.
// ---------------------------------------------------------------------------
__global__ __launch_bounds__(256)
void qkv_gemm(const f16* __restrict__ X, const f16* __restrict__ Wq,
              const f16* __restrict__ Wk, const f16* __restrict__ Wv,
              f16* __restrict__ Qo, f16* __restrict__ Ko, f16* __restrict__ Vo)
{
    const int z = blockIdx.z;
    const f16* Bw = (z == 0) ? Wq : (z == 1) ? Wk : Wv;
    f16* C = (z == 0) ? Qo : (z == 1) ? Ko : Vo;
    const int K = 2048;

    __shared__ __align__(16) f16 As[128 * 32];
    __shared__ __align__(16) f16 Bs[128 * 32];

    const int tid = threadIdx.x;
    const int wave = tid >> 6, lane = tid & 63;
    const int lrow = lane & 15, lquad = lane >> 4;
    const int wr = wave >> 1, wc = wave & 1;
    const int m0 = blockIdx.y * 128, n0 = blockIdx.x * 128;

    f32x4 acc[4][4];
    const f32x4 z4 = {0.f, 0.f, 0.f, 0.f};
    for (int i = 0; i < 4; i++) for (int j = 0; j < 4; j++) acc[i][j] = z4;

    for (int k0 = 0; k0 < K; k0 += 32) {
        __syncthreads();                       // prior ds_reads done
        for (int i = 0; i < 2; i++) {
            int sb = i * 256 + wave * 64;      // wave-uniform slot base
            int slot = sb + lane;
            int row = slot >> 2, kc = slot & 3;
            load_lds16(X  + (size_t)(m0 + row) * K + k0 + kc * 8, As + sb * 8);
            load_lds16(Bw + (size_t)(n0 + row) * K + k0 + kc * 8, Bs + sb * 8);
        }
        __syncthreads();                       // staging complete
        f16x8 af[4], bfr[4];
        for (int mt = 0; mt < 4; mt++)
            af[mt]  = *(const f16x8*)(As + (wr * 64 + mt * 16 + lrow) * 32 + lquad * 8);
        for (int nt = 0; nt < 4; nt++)
            bfr[nt] = *(const f16x8*)(Bs + (wc * 64 + nt * 16 + lrow) * 32 + lquad * 8);
        for (int mt = 0; mt < 4; mt++)
            for (int nt = 0; nt < 4; nt++)
                acc[mt][nt] = __builtin_amdgcn_mfma_f32_16x16x32_f16(af[mt], bfr[nt], acc[mt][nt], 0, 0, 0);
    }

    if (z < 2) {
        for (int mt = 0; mt < 4; mt++) {
            int mbase = m0 + wr * 64 + mt * 16 + lquad * 4;
            for (int r = 0; r < 4; r++) {
                int m = mbase + r;
                int b = m >> 11, s = m & 2047;
                for (int nt = 0; nt < 4; nt++) {
                    int n = n0 + wc * 64 + nt * 16 + lrow;
                    int h = n >> 7, d = n & 127;
                    C[(size_t)(((b * 4 + h) << 11) + s) * 128 + d] = (f16)acc[mt][nt][r];
                }
            }
        }
    } else {
        for (int mt = 0; mt < 4; mt++) {
            int mbase = m0 + wr * 64 + mt * 16 + lquad * 4;
            int b = mbase >> 11, s = mbase & 2047;
            for (int nt = 0; nt < 4; nt++) {
                int n = n0 + wc * 64 + nt * 16 + lrow;
                int h = n >> 7, d = n & 127;
                f16x4 pk;
                for (int r = 0; r < 4; r++) pk[r] = (f16)acc[mt][nt][r];
                *(f16x4*)(C + ((size_t)((b * 4 + h) * 128 + d) << 11) + s) = pk;
            }
        }
    }
}

// ---------------------------------------------------------------------------
// Sliding-window attention, one wave per 16 query rows (unchanged from R5).
// Q,K: (B,4,S,D); V: (B,4,D,S) transposed; AO: (B,S,512)
// ---------------------------------------------------------------------------
__global__ __launch_bounds__(64)
void attn_win(const f16* __restrict__ Q, const f16* __restrict__ Kc,
              const f16* __restrict__ Vt, f16* __restrict__ AO)
{
    const int bg = blockIdx.y;
    const int b = bg >> 2, g = bg & 3;
    const int qbase = blockIdx.x * 16;
    const int lane = threadIdx.x;
    const int lrow = lane & 15, lquad = lane >> 4;

    const f16* Qb = Q  + (size_t)(b * 4 + g) * (2048 * 128);
    const f16* Kb = Kc + (size_t)(b * 4 + g) * (2048 * 128);
    const f16* Vb = Vt + (size_t)(b * 4 + g) * (128 * 2048);

    __shared__ __align__(16) f16 Pl[16 * 128];

    f16x8 qf[4];
    for (int ks = 0; ks < 4; ks++)
        qf[ks] = *(const f16x8*)(Qb + (size_t)(qbase + lrow) * 128 + ks * 32 + lquad * 8);

    float m_i[4], l_i[4];
    f32x4 oa[8];
    const f32x4 z4 = {0.f, 0.f, 0.f, 0.f};
    for (int r = 0; r < 4; r++) { m_i[r] = -30000.f; l_i[r] = 0.f; }
    for (int nt = 0; nt < 8; nt++) oa[nt] = z4;

    const int t0 = (qbase >= 256) ? (((qbase - 255) >> 7) << 7) : 0;
    for (int kt = t0; kt <= qbase + 15; kt += 128) {
        f32x4 sc[8];
        for (int nt = 0; nt < 8; nt++) sc[nt] = z4;
        for (int nt = 0; nt < 8; nt++) {
            for (int ks = 0; ks < 4; ks++) {
                f16x8 kf = *(const f16x8*)(Kb + (size_t)(kt + nt * 16 + lrow) * 128 + ks * 32 + lquad * 8);
                sc[nt] = __builtin_amdgcn_mfma_f32_16x16x32_f16(qf[ks], kf, sc[nt], 0, 0, 0);
            }
        }
        for (int r = 0; r < 4; r++) {
            const int qi = qbase + lquad * 4 + r;
            float rmax = -60000.f;
            for (int nt = 0; nt < 8; nt++) {
                int kj = kt + nt * 16 + lrow;
                float sval = sc[nt][r];
                bool ok = (kj <= qi) && (kj + 256 > qi);
                sval = ok ? sval : -60000.f;
                sc[nt][r] = sval;
                rmax = fmaxf(rmax, sval);
            }
            rmax = fmaxf(rmax, __shfl_xor(rmax, 1));
            rmax = fmaxf(rmax, __shfl_xor(rmax, 2));
            rmax = fmaxf(rmax, __shfl_xor(rmax, 4));
            rmax = fmaxf(rmax, __shfl_xor(rmax, 8));
            float mold = m_i[r];
            float mnew = fmaxf(mold, rmax);
            float alpha = __expf(mold - mnew);
            m_i[r] = mnew;
            float rsum = 0.f;
            for (int nt = 0; nt < 8; nt++) {
                float p = __expf(sc[nt][r] - mnew);
                sc[nt][r] = p;
                rsum += p;
            }
            rsum += __shfl_xor(rsum, 1);
            rsum += __shfl_xor(rsum, 2);
            rsum += __shfl_xor(rsum, 4);
            rsum += __shfl_xor(rsum, 8);
            l_i[r] = l_i[r] * alpha + rsum;
            for (int nt = 0; nt < 8; nt++) oa[nt][r] *= alpha;
        }
        for (int nt = 0; nt < 8; nt++)
            for (int r = 0; r < 4; r++)
                Pl[(lquad * 4 + r) * 128 + nt * 16 + lrow] = (f16)sc[nt][r];
        __syncthreads();
        f16x8 pf[4];
        for (int ks = 0; ks < 4; ks++)
            pf[ks] = *(const f16x8*)(Pl + lrow * 128 + ks * 32 + lquad * 8);
        for (int nt = 0; nt < 8; nt++) {
            for (int ks = 0; ks < 4; ks++) {
                f16x8 vf = *(const f16x8*)(Vb + (size_t)(nt * 16 + lrow) * 2048 + kt + ks * 32 + lquad * 8);
                oa[nt] = __builtin_amdgcn_mfma_f32_16x16x32_f16(pf[ks], vf, oa[nt], 0, 0, 0);
            }
        }
        __syncthreads();
    }
    float inv[4];
    for (int r = 0; r < 4; r++) inv[r] = (l_i[r] > 0.f) ? 1.f / l_i[r] : 0.f;
    for (int nt = 0; nt < 8; nt++) {
        for (int r = 0; r < 4; r++) {
            int q = qbase + lquad * 4 + r;
            int d = nt * 16 + lrow;
            AO[(size_t)(b * 2048 + q) * 512 + g * 128 + d] = (f16)(oa[nt][r] * inv[r]);
        }
    }
}

// ---------------------------------------------------------------------------
// Output GEMM (f16 in via global_load_lds): out = AO @ Wr^T + bo, f32 out.
// M=4096, N=2048, K=512.
// ---------------------------------------------------------------------------
__global__ __launch_bounds__(256)
void out_gemm(const f16* __restrict__ A, const f16* __restrict__ Bw,
              const float* __restrict__ bias, float* __restrict__ C)
{
    const int K = 512, N = 2048;
    __shared__ __align__(16) f16 As[128 * 32];
    __shared__ __align__(16) f16 Bs[128 * 32];

    const int tid = threadIdx.x;
    const int wave = tid >> 6, lane = tid & 63;
    const int lrow = lane & 15, lquad = lane >> 4;
    const int wr = wave >> 1, wc = wave & 1;
    const int m0 = blockIdx.y * 128, n0 = blockIdx.x * 128;

    f32x4 acc[4][4];
    const f32x4 z4 = {0.f, 0.f, 0.f, 0.f};
    for (int i = 0; i < 4; i++) for (int j = 0; j < 4; j++) acc[i][j] = z4;

    for (int k0 = 0; k0 < K; k0 += 32) {
        __syncthreads();
        for (int i = 0; i < 2; i++) {
            int sb = i * 256 + wave * 64;
            int slot = sb + lane;
            int row = slot >> 2, kc = slot & 3;
            load_lds16(A  + (size_t)(m0 + row) * K + k0 + kc * 8, As + sb * 8);
            load_lds16(Bw + (size_t)(n0 + row) * K + k0 + kc * 8, Bs + sb * 8);
        }
        __syncthreads();
        f16x8 af[4], bfr[4];
        for (int mt = 0; mt < 4; mt++)
            af[mt]  = *(const f16x8*)(As + (wr * 64 + mt * 16 + lrow) * 32 + lquad * 8);
        for (int nt = 0; nt < 4; nt++)
            bfr[nt] = *(const f16x8*)(Bs + (wc * 64 + nt * 16 + lrow) * 32 + lquad * 8);
        for (int mt = 0; mt < 4; mt++)
            for (int nt = 0; nt < 4; nt++)
                acc[mt][nt] = __builtin_amdgcn_mfma_f32_16x16x32_f16(af[mt], bfr[nt], acc[mt][nt], 0, 0, 0);
    }

    for (int nt = 0; nt < 4; nt++) {
        int n = n0 + wc * 64 + nt * 16 + lrow;
        float bv2 = bias[n];
        for (int mt = 0; mt < 4; mt++) {
            int mbase = m0 + wr * 64 + mt * 16 + lquad * 4;
            for (int r = 0; r < 4; r++)
                C[(size_t)(mbase + r) * N + n] = acc[mt][nt][r] + bv2;
        }
    }
}

// ---------------------------------------------------------------------------
extern "C" void kernel_launch(void* const* d_in, const int* in_sizes, int n_in,
                              void* d_out, int out_size, void* d_ws, size_t ws_size,
                              hipStream_t stream)
{
    const float* x  = (const float*)d_in[0];
    const float* Wq = (const float*)d_in[1];
    const float* Wk = (const float*)d_in[2];
    const float* Wv = (const float*)d_in[3];
    const float* Wo = (const float*)d_in[4];
    const float* bo = (const float*)d_in[5];
    float* out = (float*)d_out;

    f16* Xh  = (f16*)d_ws;             // 8388608 (X as f16) — dead after qkv_gemm
    f16* AO  = Xh;                     // alias: AO (2097152) reuses Xh region
    f16* Wqh = Xh  + 8388608;          // 1048576
    f16* Wkh = Wqh + 1048576;          // 1048576
    f16* Wvh = Wkh + 1048576;          // 1048576
    f16* Wr  = Wvh + 1048576;          // 1048576 (folded Wo)
    f16* Qws = Wr  + 1048576;          // 2097152 (B,4,S,D)
    f16* Kws = Qws + 2097152;          // 2097152
    f16* Vws = Kws + 2097152;          // 2097152 (B,4,D,S)
    // total 18,874,368 f16 = 36 MiB

    cvt_fold<<<dim3(12288), 256, 0, stream>>>(x, Wq, Wk, Wv, Wo, Xh, Wqh, Wkh, Wvh, Wr);
    qkv_gemm<<<dim3(4, 32, 3), 256, 0, stream>>>(Xh, Wqh, Wkh, Wvh, Qws, Kws, Vws);
    attn_win<<<dim3(128, 8), 64, 0, stream>>>(Qws, Kws, Vws, AO);
    out_gemm<<<dim3(16, 32), 256, 0, stream>>>(AO, Wr, bo, out);
}